// Round 1
// baseline (2481.946 us; speedup 1.0000x reference)
//
#include <hip/hip_runtime.h>
#include <math.h>

#define NIMG 16
#define NQI  1000
#define NCC  80
#define NGG  200
#define RR   201      // NG+1 rows
#define NWG  16       // workgroups per image
#define CPW  63       // columns per WG (16*63 >= 1000)
#define NTHR 1024
#define NITER 100

#define LOG2E  1.4426950408889634f
#define SC     14.426950408889634f   /* log2(e)/EPS, EPS=0.1 */
#define U2INIT 14.426950408889634f   /* (1/EPS)*log2(e): u0 = 1 */

// online log2-sum-exp accumulate: state (m = running max, s = sum of 2^(x-m))
__device__ __forceinline__ void lse_acc(float& m, float& s, float x) {
    float M = fmaxf(m, x);
    s = s * exp2f(m - M) + exp2f(x - M);
    m = M;
}
__device__ __forceinline__ void lse_mrg(float& m, float& s, float om, float os) {
    float M = fmaxf(m, om);
    s = s * exp2f(m - M) + os * exp2f(om - M);
    m = M;
}

// per-image generation barrier over 16 co-resident blocks (device-scope atomics)
__device__ __forceinline__ void img_barrier(unsigned* c, unsigned target) {
    __syncthreads();
    if (threadIdx.x == 0) {
        __threadfence();
        __hip_atomic_fetch_add(c, 1u, __ATOMIC_RELEASE, __HIP_MEMORY_SCOPE_AGENT);
        int spins = 0;
        while (__hip_atomic_load(c, __ATOMIC_ACQUIRE, __HIP_MEMORY_SCOPE_AGENT) < target) {
            if (++spins > (1 << 22)) break;   // safety valve: never hard-hang
        }
    }
    __syncthreads();
}

extern "C" __global__ void __launch_bounds__(NTHR, 1)
ota_kernel(const float* __restrict__ logits,   // [16][1000][80]
           const float* __restrict__ pboxes,   // [16][1000][4]
           const int*   __restrict__ gcls,     // [16][200]
           const float* __restrict__ gboxes,   // [16][200][4]
           const float* __restrict__ imsz,     // [16][4]
           const float* __restrict__ imszt,    // [16][200][4]
           float* __restrict__ out,            // pi [16][201][1000] ++ matched [16][1000]
           unsigned* __restrict__ cnt,         // [16] barrier counters (zeroed per call)
           float* __restrict__ pms,            // [2][16][201][16][2] row-LSE partials (m,s)
           float* __restrict__ pmx)            // [16][201][16] row-max partials
{
    const int tid = threadIdx.x;
    const int bid = blockIdx.x;
    // XCD-aware mapping: the 16 WGs of an image land on one XCD (locality heuristic only)
    const int img = (bid & 7) * 2 + ((bid >> 3) >> 4);
    const int wg  = (bid >> 3) & 15;
    const int q0  = wg * CPW;
    const int ncols = min(CPW, NQI - q0);

    __shared__ float sE[CPW][RR];   // E2 chunk, [col][row] (stride 201 -> <=3-way banks)
    __shared__ float sU[RR];
    __shared__ float sV[CPW];
    __shared__ float sRM[RR];
    __shared__ float sNS[CPW];
    __shared__ float sTB[NGG][4];   // gt boxes / image size
    __shared__ float sGB[NGG][4];   // raw gt boxes
    __shared__ float sGA[NGG];      // raw gt areas
    __shared__ int   sCL[NGG];

    const float LMU2 = log2f(200.0f);   // log_mu for fg rows; bg row: log(1+1e-8)=0 in fp32

    // ---- stage gt data into LDS ----
    for (int g = tid; g < NGG; g += NTHR) {
        const float* gb = gboxes + ((size_t)img * NGG + g) * 4;
        const float* t4 = imszt + ((size_t)img * NGG + g) * 4;
        float b0 = gb[0], b1 = gb[1], b2 = gb[2], b3 = gb[3];
        sGB[g][0] = b0; sGB[g][1] = b1; sGB[g][2] = b2; sGB[g][3] = b3;
        sTB[g][0] = b0 / t4[0]; sTB[g][1] = b1 / t4[1];
        sTB[g][2] = b2 / t4[2]; sTB[g][3] = b3 / t4[3];
        sGA[g] = (b2 - b0) * (b3 - b1);
        sCL[g] = gcls[(size_t)img * NGG + g];
    }
    if (tid < RR) sU[tid] = U2INIT;
    __syncthreads();

    const int col  = tid >> 4;   // 0..63, 16 threads per column
    const int part = tid & 15;
    const int q    = q0 + col;

    // ---- neg_sum[q] = sum_c (1-ALPHA)*softplus(l)*sigmoid(l)^2 ----
    float ns = 0.f;
    if (col < ncols) {
        const float* lp = logits + ((size_t)img * NQI + q) * NCC;
        for (int c = part; c < NCC; c += 16) {
            float l = lp[c];
            float p = 1.f / (1.f + exp2f(-l * LOG2E));
            float spl = fmaxf(l, 0.f) + log1pf(expf(-fabsf(l)));
            ns += 0.75f * spl * p * p;
        }
    }
    for (int k = 1; k < 16; k <<= 1) ns += __shfl_xor(ns, k);
    if (col < ncols && part == 0) sNS[col] = ns;
    __syncthreads();

    // ---- build E2[col][g] = -loss[g][q] * log2e/EPS ----
    if (col < ncols) {
        const float* pp = pboxes + ((size_t)img * NQI + q) * 4;
        float pb0 = pp[0], pb1 = pp[1], pb2 = pp[2], pb3 = pp[3];
        float ab  = (pb2 - pb0) * (pb3 - pb1);
        float nsq = sNS[col];
        float ob0 = pb0 / imsz[img*4+0], ob1 = pb1 / imsz[img*4+1];
        float ob2 = pb2 / imsz[img*4+2], ob3 = pb3 / imsz[img*4+3];
        const float* lp = logits + ((size_t)img * NQI + q) * NCC;
        for (int g = part; g < NGG; g += 16) {
            // focal (pos-neg) at the target class, on the fly (L1-resident logit row)
            float l = lp[sCL[g]];
            float p = 1.f / (1.f + exp2f(-l * LOG2E));
            float t0 = log1pf(expf(-fabsf(l)));
            float spl  = fmaxf(l, 0.f) + t0;   // softplus(l)
            float spml = spl - l;              // softplus(-l)
            float pos = 0.25f * spml * (1.f - p) * (1.f - p);
            float neg = 0.75f * spl * p * p;
            float lcls = nsq + (pos - neg);
            float cb = fabsf(sTB[g][0]-ob0) + fabsf(sTB[g][1]-ob1)
                     + fabsf(sTB[g][2]-ob2) + fabsf(sTB[g][3]-ob3);
            float g0 = sGB[g][0], g1 = sGB[g][1], g2 = sGB[g][2], g3 = sGB[g][3];
            float iwd = fminf(g2, pb2) - fmaxf(g0, pb0);
            float ihd = fminf(g3, pb3) - fmaxf(g1, pb1);
            float inter = fmaxf(iwd, 0.f) * fmaxf(ihd, 0.f);
            float uni = sGA[g] + ab - inter;
            float iou = inter / uni;
            float cwd = fmaxf(g2, pb2) - fminf(g0, pb0);
            float chd = fmaxf(g3, pb3) - fminf(g1, pb1);
            float ac = fmaxf(cwd, 0.f) * fmaxf(chd, 0.f);
            float giou = iou - (ac - uni) / ac;
            float loss = 2.f * lcls + 5.f * cb - 2.f * giou;
            sE[col][g] = -loss * SC;
        }
        if (part == 0) sE[col][NGG] = -nsq * SC;   // background row: CBG * neg_sum
    }
    __syncthreads();

    // ---- 100 Sinkhorn iterations ----
    for (int it = 0; it < NITER; ++it) {
        // Phase A: V[q] = -LSE2_g(E2 + U2)   (WG-local, 16 threads/column)
        float m = -1e30f, s = 0.f;
        if (col < ncols) {
            for (int r = part; r < RR; r += 16)
                lse_acc(m, s, sE[col][r] + sU[r]);
        }
        for (int k = 1; k < 16; k <<= 1) {
            float om = __shfl_xor(m, k), os = __shfl_xor(s, k);
            lse_mrg(m, s, om, os);
        }
        if (col < ncols && part == 0) sV[col] = -(m + log2f(s));
        __syncthreads();

        // Phase B: per-row partial LSE over this WG's columns -> global (m,s)
        float* pb = pms + ((size_t)(it & 1) * NIMG + img) * (RR * NWG * 2);
        {
            int r2 = tid >> 2, h = tid & 3;
            m = -1e30f; s = 0.f;
            if (r2 < RR) {
                for (int j = h; j < ncols; j += 4)
                    lse_acc(m, s, sE[j][r2] + sV[j]);
            }
            for (int k = 1; k < 4; k <<= 1) {
                float om = __shfl_xor(m, k), os = __shfl_xor(s, k);
                lse_mrg(m, s, om, os);
            }
            if (r2 < RR && h == 0) {
                __hip_atomic_store(&pb[(r2*NWG + wg)*2 + 0], m, __ATOMIC_RELAXED, __HIP_MEMORY_SCOPE_AGENT);
                __hip_atomic_store(&pb[(r2*NWG + wg)*2 + 1], s, __ATOMIC_RELAXED, __HIP_MEMORY_SCOPE_AGENT);
            }
        }
        img_barrier(&cnt[img], (unsigned)NWG * (it + 1));

        // Phase C: each WG redundantly combines 16 partials -> U2
        if (tid < RR) {
            float cm = -1e30f, cs = 0.f;
            for (int w = 0; w < NWG; ++w) {
                float om = __hip_atomic_load(&pb[(tid*NWG + w)*2 + 0], __ATOMIC_RELAXED, __HIP_MEMORY_SCOPE_AGENT);
                float os = __hip_atomic_load(&pb[(tid*NWG + w)*2 + 1], __ATOMIC_RELAXED, __HIP_MEMORY_SCOPE_AGENT);
                lse_mrg(cm, cs, om, os);
            }
            sU[tid] = (tid < NGG ? LMU2 : 0.f) - (cm + log2f(cs));
        }
        __syncthreads();
    }

    // ---- row max of X2 = E2+U2+V2 (for pi / pi.max(axis=1)) ----
    {
        int r2 = tid >> 2, h = tid & 3;
        float m = -1e30f;
        if (r2 < RR) {
            for (int j = h; j < ncols; j += 4)
                m = fmaxf(m, sE[j][r2] + sV[j]);
        }
        for (int k = 1; k < 4; k <<= 1) m = fmaxf(m, __shfl_xor(m, k));
        if (r2 < RR && h == 0)
            __hip_atomic_store(&pmx[((size_t)img*RR + r2)*NWG + wg], m + sU[r2],
                               __ATOMIC_RELAXED, __HIP_MEMORY_SCOPE_AGENT);
    }
    img_barrier(&cnt[img], (unsigned)NWG * (NITER + 1));
    if (tid < RR) {
        float M = -1e30f;
        for (int w = 0; w < NWG; ++w)
            M = fmaxf(M, __hip_atomic_load(&pmx[((size_t)img*RR + tid)*NWG + w],
                                           __ATOMIC_RELAXED, __HIP_MEMORY_SCOPE_AGENT));
        sRM[tid] = M;
    }
    __syncthreads();

    // ---- outputs ----
    if (col < ncols) {
        float vv = sV[col];
        for (int r = part; r < RR; r += 16) {
            float x = sE[col][r] + sU[r] + vv - sRM[r];
            out[((size_t)img * RR + r) * NQI + q] = exp2f(x);
        }
        if (part == 0) {
            float best = -1e30f; int bi = 0;
            for (int r = 0; r < RR; ++r) {
                float x = sE[col][r] + sU[r] - sRM[r];  // vv constant over r: argmax-invariant
                if (x > best) { best = x; bi = r; }      // strict > : numpy first-index ties
            }
            out[(size_t)NIMG * RR * NQI + (size_t)img * NQI + q] = (float)bi;
        }
    }
}

extern "C" void kernel_launch(void* const* d_in, const int* in_sizes, int n_in,
                              void* d_out, int out_size, void* d_ws, size_t ws_size,
                              hipStream_t stream) {
    const float* logits = (const float*)d_in[0];
    const float* pboxes = (const float*)d_in[1];
    const int*   gcls   = (const int*)  d_in[2];
    const float* gboxes = (const float*)d_in[3];
    const float* imsz   = (const float*)d_in[4];
    const float* imszt  = (const float*)d_in[5];
    float* out = (float*)d_out;

    unsigned* cnt = (unsigned*)d_ws;
    float* pms = (float*)((char*)d_ws + 256);                       // 2*16*201*16*2*4 = 823296 B
    float* pmx = (float*)((char*)d_ws + 256 + 2*NIMG*RR*NWG*2*4);   // 16*201*16*4    = 205824 B

    // barrier counters must start at 0 every call (graph replays don't re-poison)
    hipMemsetAsync(d_ws, 0, NIMG * sizeof(unsigned), stream);

    ota_kernel<<<dim3(256), dim3(NTHR), 0, stream>>>(
        logits, pboxes, gcls, gboxes, imsz, imszt, out, cnt, pms, pmx);
}

// Round 2
// 883.106 us; speedup vs baseline: 2.8105x; 2.8105x over previous
//
#include <hip/hip_runtime.h>
#include <math.h>

#define NIMG 16
#define NQI  1000
#define NCC  80
#define NGG  200
#define RR   201      // NG+1 rows
#define NWG  16       // workgroups per image
#define CPW  63       // columns per WG (16*63 >= 1000)
#define NTHR 1024
#define NITER 100

#define LOG2E  1.4426950408889634f
#define SC     14.426950408889634f   /* log2(e)/EPS, EPS=0.1 */
#define U2INIT 14.426950408889634f   /* (1/EPS)*log2(e): u0 = 1 */

union MS { unsigned long long u; float2 f; };

// All-RELAXED per-image barrier. Correctness: __syncthreads() drains each
// wave's vmcnt (verified compiler behavior: s_waitcnt vmcnt(0) before
// s_barrier), so every wave's agent-scope (L2-bypassing) partial stores are
// ack'd at the coherence point (L3) before thread 0's counter add becomes
// visible. No threadfence / acquire / release => no buffer_wbl2 / buffer_inv
// in the iteration loop (round-1's 336MB WRITE_SIZE pathology).
__device__ __forceinline__ void img_barrier(unsigned* c, unsigned target) {
    __syncthreads();
    if (threadIdx.x == 0) {
        __hip_atomic_fetch_add(c, 1u, __ATOMIC_RELAXED, __HIP_MEMORY_SCOPE_AGENT);
        int spins = 0;
        while (__hip_atomic_load(c, __ATOMIC_RELAXED, __HIP_MEMORY_SCOPE_AGENT) < target) {
            if (++spins > (1 << 22)) break;   // safety valve: never hard-hang
        }
    }
    __syncthreads();
}

extern "C" __global__ void __launch_bounds__(NTHR, 1)
ota_kernel(const float* __restrict__ logits,   // [16][1000][80]
           const float* __restrict__ pboxes,   // [16][1000][4]
           const int*   __restrict__ gcls,     // [16][200]
           const float* __restrict__ gboxes,   // [16][200][4]
           const float* __restrict__ imsz,     // [16][4]
           const float* __restrict__ imszt,    // [16][200][4]
           float* __restrict__ out,            // pi [16][201][1000] ++ matched [16][1000]
           unsigned* __restrict__ cnt,         // [16*16] barrier counters, 64B-strided
           unsigned long long* __restrict__ pms, // [2][16][201][16] packed (max,sum)
           float* __restrict__ pmx)            // [16][201][16] row-max partials
{
    const int tid = threadIdx.x;
    const int bid = blockIdx.x;
    // all 16 WGs of an image share bid&7 -> same XCD under round-robin (perf heuristic only)
    const int img = (bid & 7) * 2 + ((bid >> 3) >> 4);
    const int wg  = (bid >> 3) & 15;
    const int q0  = wg * CPW;
    const int ncols = min(CPW, NQI - q0);
    unsigned* myc = cnt + img * 16;

    __shared__ float sE[CPW][RR];   // E2 chunk, [col][row]
    __shared__ float sU[RR];
    __shared__ float sV[CPW];
    __shared__ float sRM[RR];
    __shared__ float sNS[CPW];
    __shared__ float sTB[NGG][4];   // gt boxes / image size
    __shared__ float sGB[NGG][4];   // raw gt boxes
    __shared__ float sGA[NGG];      // raw gt areas
    __shared__ int   sCL[NGG];

    const float LMU2 = log2f(200.0f);   // log_mu fg rows; bg row: log(1+1e-8)=0 in fp32

    // ---- stage gt data into LDS ----
    for (int g = tid; g < NGG; g += NTHR) {
        const float* gb = gboxes + ((size_t)img * NGG + g) * 4;
        const float* t4 = imszt + ((size_t)img * NGG + g) * 4;
        float b0 = gb[0], b1 = gb[1], b2 = gb[2], b3 = gb[3];
        sGB[g][0] = b0; sGB[g][1] = b1; sGB[g][2] = b2; sGB[g][3] = b3;
        sTB[g][0] = b0 / t4[0]; sTB[g][1] = b1 / t4[1];
        sTB[g][2] = b2 / t4[2]; sTB[g][3] = b3 / t4[3];
        sGA[g] = (b2 - b0) * (b3 - b1);
        sCL[g] = gcls[(size_t)img * NGG + g];
    }
    if (tid < RR) sU[tid] = U2INIT;
    __syncthreads();

    const int col  = tid >> 4;   // 0..63, 16 threads per column
    const int part = tid & 15;
    const int q    = q0 + col;

    // ---- neg_sum[q] ----
    float ns = 0.f;
    if (col < ncols) {
        const float* lp = logits + ((size_t)img * NQI + q) * NCC;
        for (int c = part; c < NCC; c += 16) {
            float l = lp[c];
            float p = 1.f / (1.f + exp2f(-l * LOG2E));
            float spl = fmaxf(l, 0.f) + log1pf(expf(-fabsf(l)));
            ns += 0.75f * spl * p * p;
        }
    }
    for (int k = 1; k < 16; k <<= 1) ns += __shfl_xor(ns, k);
    if (col < ncols && part == 0) sNS[col] = ns;
    __syncthreads();

    // ---- build E2[col][g] = -loss[g][q] * log2e/EPS ----
    if (col < ncols) {
        const float* pp = pboxes + ((size_t)img * NQI + q) * 4;
        float pb0 = pp[0], pb1 = pp[1], pb2 = pp[2], pb3 = pp[3];
        float ab  = (pb2 - pb0) * (pb3 - pb1);
        float nsq = sNS[col];
        float ob0 = pb0 / imsz[img*4+0], ob1 = pb1 / imsz[img*4+1];
        float ob2 = pb2 / imsz[img*4+2], ob3 = pb3 / imsz[img*4+3];
        const float* lp = logits + ((size_t)img * NQI + q) * NCC;
        for (int g = part; g < NGG; g += 16) {
            float l = lp[sCL[g]];
            float p = 1.f / (1.f + exp2f(-l * LOG2E));
            float t0 = log1pf(expf(-fabsf(l)));
            float spl  = fmaxf(l, 0.f) + t0;
            float spml = spl - l;
            float pos = 0.25f * spml * (1.f - p) * (1.f - p);
            float neg = 0.75f * spl * p * p;
            float lcls = nsq + (pos - neg);
            float cb = fabsf(sTB[g][0]-ob0) + fabsf(sTB[g][1]-ob1)
                     + fabsf(sTB[g][2]-ob2) + fabsf(sTB[g][3]-ob3);
            float g0 = sGB[g][0], g1 = sGB[g][1], g2 = sGB[g][2], g3 = sGB[g][3];
            float iwd = fminf(g2, pb2) - fmaxf(g0, pb0);
            float ihd = fminf(g3, pb3) - fmaxf(g1, pb1);
            float inter = fmaxf(iwd, 0.f) * fmaxf(ihd, 0.f);
            float uni = sGA[g] + ab - inter;
            float iou = inter / uni;
            float cwd = fmaxf(g2, pb2) - fminf(g0, pb0);
            float chd = fmaxf(g3, pb3) - fminf(g1, pb1);
            float ac = fmaxf(cwd, 0.f) * fmaxf(chd, 0.f);
            float giou = iou - (ac - uni) / ac;
            float loss = 2.f * lcls + 5.f * cb - 2.f * giou;
            sE[col][g] = -loss * SC;
        }
        if (part == 0) sE[col][NGG] = -nsq * SC;   // background row
    }
    __syncthreads();

    const int r2 = tid >> 2, h = tid & 3;   // Phase B/C decomposition: 4 threads/row

    // ---- 100 Sinkhorn iterations ----
    for (int it = 0; it < NITER; ++it) {
        // Phase A: V[q] = -LSE2_g(E2 + U2), two-pass (max, then sum-exp)
        {
            float M = -1e30f;
            if (col < ncols)
                for (int r = part; r < RR; r += 16) M = fmaxf(M, sE[col][r] + sU[r]);
            for (int k = 1; k < 16; k <<= 1) M = fmaxf(M, __shfl_xor(M, k));
            float S = 0.f;
            if (col < ncols)
                for (int r = part; r < RR; r += 16) S += exp2f(sE[col][r] + sU[r] - M);
            for (int k = 1; k < 16; k <<= 1) S += __shfl_xor(S, k);
            if (col < ncols && part == 0) sV[col] = -(M + log2f(S));
        }
        __syncthreads();

        // Phase B: per-WG per-row (max, sum) over 63 cols -> packed 8B agent store
        unsigned long long* pb = pms + ((size_t)(it & 1) * NIMG + img) * (RR * NWG);
        {
            float M = -1e30f;
            if (r2 < RR)
                for (int j = h; j < ncols; j += 4) M = fmaxf(M, sE[j][r2] + sV[j]);
            for (int k = 1; k < 4; k <<= 1) M = fmaxf(M, __shfl_xor(M, k));
            float S = 0.f;
            if (r2 < RR)
                for (int j = h; j < ncols; j += 4) S += exp2f(sE[j][r2] + sV[j] - M);
            for (int k = 1; k < 4; k <<= 1) S += __shfl_xor(S, k);
            if (r2 < RR && h == 0) {
                MS ms; ms.f.x = M; ms.f.y = S;
                __hip_atomic_store(&pb[r2 * NWG + wg], ms.u,
                                   __ATOMIC_RELAXED, __HIP_MEMORY_SCOPE_AGENT);
            }
        }
        img_barrier(myc, (unsigned)NWG * (it + 1));

        // Phase C: 4 threads/row combine 16 partials -> U2
        if (r2 < RR) {
            MS a0, a1, a2, a3;
            unsigned long long* pr = pb + r2 * NWG + h * 4;
            a0.u = __hip_atomic_load(&pr[0], __ATOMIC_RELAXED, __HIP_MEMORY_SCOPE_AGENT);
            a1.u = __hip_atomic_load(&pr[1], __ATOMIC_RELAXED, __HIP_MEMORY_SCOPE_AGENT);
            a2.u = __hip_atomic_load(&pr[2], __ATOMIC_RELAXED, __HIP_MEMORY_SCOPE_AGENT);
            a3.u = __hip_atomic_load(&pr[3], __ATOMIC_RELAXED, __HIP_MEMORY_SCOPE_AGENT);
            float gm = fmaxf(fmaxf(a0.f.x, a1.f.x), fmaxf(a2.f.x, a3.f.x));
            for (int k = 1; k < 4; k <<= 1) gm = fmaxf(gm, __shfl_xor(gm, k));
            float S = a0.f.y * exp2f(a0.f.x - gm) + a1.f.y * exp2f(a1.f.x - gm)
                    + a2.f.y * exp2f(a2.f.x - gm) + a3.f.y * exp2f(a3.f.x - gm);
            for (int k = 1; k < 4; k <<= 1) S += __shfl_xor(S, k);
            if (h == 0) sU[r2] = (r2 < NGG ? LMU2 : 0.f) - (gm + log2f(S));
        }
        __syncthreads();
    }

    // ---- row max of X2 = E2+U2+V2 ----
    {
        float M = -1e30f;
        if (r2 < RR)
            for (int j = h; j < ncols; j += 4) M = fmaxf(M, sE[j][r2] + sV[j]);
        for (int k = 1; k < 4; k <<= 1) M = fmaxf(M, __shfl_xor(M, k));
        if (r2 < RR && h == 0)
            __hip_atomic_store(&pmx[((size_t)img*RR + r2)*NWG + wg], M + sU[r2],
                               __ATOMIC_RELAXED, __HIP_MEMORY_SCOPE_AGENT);
    }
    img_barrier(myc, (unsigned)NWG * (NITER + 1));
    if (r2 < RR) {
        float M = -1e30f;
        const float* px = pmx + ((size_t)img*RR + r2)*NWG + h*4;
        for (int w = 0; w < 4; ++w)
            M = fmaxf(M, __hip_atomic_load(&px[w], __ATOMIC_RELAXED, __HIP_MEMORY_SCOPE_AGENT));
        for (int k = 1; k < 4; k <<= 1) M = fmaxf(M, __shfl_xor(M, k));
        if (h == 0) sRM[r2] = M;
    }
    __syncthreads();

    // ---- outputs ----
    if (col < ncols) {
        float vv = sV[col];
        for (int r = part; r < RR; r += 16) {
            float x = sE[col][r] + sU[r] + vv - sRM[r];
            out[((size_t)img * RR + r) * NQI + q] = exp2f(x);
        }
        if (part == 0) {
            float best = -1e30f; int bi = 0;
            for (int r = 0; r < RR; ++r) {
                float x = sE[col][r] + sU[r] - sRM[r];  // vv const over r: argmax-invariant
                if (x > best) { best = x; bi = r; }      // strict > : numpy first-index ties
            }
            out[(size_t)NIMG * RR * NQI + (size_t)img * NQI + q] = (float)bi;
        }
    }
}

extern "C" void kernel_launch(void* const* d_in, const int* in_sizes, int n_in,
                              void* d_out, int out_size, void* d_ws, size_t ws_size,
                              hipStream_t stream) {
    const float* logits = (const float*)d_in[0];
    const float* pboxes = (const float*)d_in[1];
    const int*   gcls   = (const int*)  d_in[2];
    const float* gboxes = (const float*)d_in[3];
    const float* imsz   = (const float*)d_in[4];
    const float* imszt  = (const float*)d_in[5];
    float* out = (float*)d_out;

    unsigned* cnt = (unsigned*)d_ws;                                   // 16 ctrs, 64B apart
    unsigned long long* pms = (unsigned long long*)((char*)d_ws + 1024); // 2*16*201*16*8 = 823296 B
    float* pmx = (float*)((char*)d_ws + 1024 + 2ull*NIMG*RR*NWG*8);      // 16*201*16*4 = 205824 B

    // barrier counters must start at 0 every call (graph replays don't re-poison)
    hipMemsetAsync(d_ws, 0, 1024, stream);

    ota_kernel<<<dim3(256), dim3(NTHR), 0, stream>>>(
        logits, pboxes, gcls, gboxes, imsz, imszt, out, cnt, pms, pmx);
}

// Round 3
// 534.940 us; speedup vs baseline: 4.6397x; 1.6508x over previous
//
#include <hip/hip_runtime.h>
#include <math.h>

#define NIMG 16
#define NQI  1000
#define NCC  80
#define NGG  200
#define RR   201      // 200 fg rows + 1 bg row
#define NR   208      // rows padded to 16*13
#define RPT  13       // rows per part-lane
#define NWG  16       // workgroups per image
#define CPW  63       // columns per WG
#define NTHR 1024
#define NITER 100
#define LDW  68       // sA row stride (floats): 16B-aligned rows, odd/32 banks

#define LOG2E  1.4426950408889634f
#define SC     14.426950408889634f   /* log2(e)/EPS, EPS=0.1 */
#define U2INIT 14.426950408889634f   /* u0 = 1 in log2/EPS units */
#define NEG    -1e30f                /* finite -inf: NEG+NEG is finite, no NaN */

union MS { unsigned long long u; float2 f; };

// All-RELAXED per-image barrier (validated round 2): __syncthreads drains each
// wave's vmcnt before s_barrier, so agent-scope partial stores are at the
// coherence point before thread 0's counter add. No wbl2/inv traffic.
__device__ __forceinline__ void img_barrier(unsigned* c, unsigned target) {
    __syncthreads();
    if (threadIdx.x == 0) {
        __hip_atomic_fetch_add(c, 1u, __ATOMIC_RELAXED, __HIP_MEMORY_SCOPE_AGENT);
        int spins = 0;
        while (__hip_atomic_load(c, __ATOMIC_RELAXED, __HIP_MEMORY_SCOPE_AGENT) < target) {
            if (++spins > (1 << 22)) break;   // safety valve: never hard-hang
        }
    }
    __syncthreads();
}

extern "C" __global__ void __launch_bounds__(NTHR, 1)
ota_kernel(const float* __restrict__ logits,   // [16][1000][80]
           const float* __restrict__ pboxes,   // [16][1000][4]
           const int*   __restrict__ gcls,     // [16][200]
           const float* __restrict__ gboxes,   // [16][200][4]
           const float* __restrict__ imsz,     // [16][4]
           const float* __restrict__ imszt,    // [16][200][4]
           float* __restrict__ out,            // pi [16][201][1000] ++ matched [16][1000]
           unsigned* __restrict__ cnt,         // [16*16] barrier counters
           unsigned long long* __restrict__ pms, // [2][16][201][16] packed (max,sum)
           float* __restrict__ pmx)            // [16][201][16] row-max partials
{
    const int tid = threadIdx.x;
    const int bid = blockIdx.x;
    const int img = (bid & 7) * 2 + ((bid >> 3) >> 4);  // 16 WGs/image on one XCD
    const int wg  = (bid >> 3) & 15;
    const int q0  = wg * CPW;
    const int ncols = min(CPW, NQI - q0);
    unsigned* myc = cnt + img * 16;

    // sA serves three roles: (1) pre-loop geometry tables, (2) per-iter raw
    // dump tile [NR][LDW], (3) output transpose buffer. 208*68*4 = 56.6 KB.
    __shared__ __align__(16) float sA[NR * LDW];
    __shared__ float sU[NR];
    __shared__ float sRM[NR];

    float4* sTB4 = (float4*)sA;           // [200] gt boxes / image size
    float4* sGB4 = (float4*)(sA + 800);   // [200] raw gt boxes
    float*  sGA  = sA + 1600;             // [200] raw gt areas
    int*    sCL  = (int*)(sA + 1800);     // [200] gt classes

    const float LMU2 = log2f(200.0f);     // fg log_mu; bg: log(1+1e-8)=0 in fp32

    for (int g = tid; g < NGG; g += NTHR) {
        float4 gb = *(const float4*)(gboxes + ((size_t)img * NGG + g) * 4);
        float4 t4 = *(const float4*)(imszt  + ((size_t)img * NGG + g) * 4);
        sGB4[g] = gb;
        sTB4[g] = make_float4(gb.x / t4.x, gb.y / t4.y, gb.z / t4.z, gb.w / t4.w);
        sGA[g] = (gb.z - gb.x) * (gb.w - gb.y);
        sCL[g] = gcls[(size_t)img * NGG + g];
    }
    if (tid < NR) sU[tid] = (tid < RR) ? U2INIT : NEG;
    __syncthreads();

    const int col  = tid >> 4;   // 0..63 (col 63 and cols>=ncols are padding)
    const int part = tid & 15;
    const int q    = q0 + col;
    const int r0   = part * RPT; // this thread's first row

    const float* lp = logits + ((size_t)img * NQI + q) * NCC;  // deref only if col<ncols

    // ---- neg_sum[q] (all 16 part-lanes share via butterfly) ----
    float ns = 0.f;
    if (col < ncols) {
        for (int c = part; c < NCC; c += 16) {
            float l = lp[c];
            float p = 1.f / (1.f + exp2f(-l * LOG2E));
            float spl = fmaxf(l, 0.f) + log1pf(expf(-fabsf(l)));
            ns += 0.75f * spl * p * p;
        }
    }
    #pragma unroll
    for (int k = 1; k < 16; k <<= 1) ns += __shfl_xor(ns, k);

    // ---- E in registers: e[i] = -loss[r0+i][q] * SC ----
    float e[RPT];
    {
        float4 isz = *(const float4*)(imsz + img * 4);
        float4 pp = make_float4(0.f, 0.f, 0.f, 0.f);
        float ab = 0.f, ob0 = 0.f, ob1 = 0.f, ob2 = 0.f, ob3 = 0.f;
        if (col < ncols) {
            pp = *(const float4*)(pboxes + ((size_t)img * NQI + q) * 4);
            ab  = (pp.z - pp.x) * (pp.w - pp.y);
            ob0 = pp.x / isz.x; ob1 = pp.y / isz.y; ob2 = pp.z / isz.z; ob3 = pp.w / isz.w;
        }
        #pragma unroll
        for (int i = 0; i < RPT; ++i) {
            int g = r0 + i;
            float val = NEG;
            if (col < ncols) {
                if (g < NGG) {
                    float l = lp[sCL[g]];
                    float p = 1.f / (1.f + exp2f(-l * LOG2E));
                    float t0 = log1pf(expf(-fabsf(l)));
                    float spl  = fmaxf(l, 0.f) + t0;
                    float spml = spl - l;
                    float pos = 0.25f * spml * (1.f - p) * (1.f - p);
                    float neg = 0.75f * spl * p * p;
                    float lcls = ns + (pos - neg);
                    float4 tb = sTB4[g];
                    float cb = fabsf(tb.x - ob0) + fabsf(tb.y - ob1)
                             + fabsf(tb.z - ob2) + fabsf(tb.w - ob3);
                    float4 gb = sGB4[g];
                    float iwd = fminf(gb.z, pp.z) - fmaxf(gb.x, pp.x);
                    float ihd = fminf(gb.w, pp.w) - fmaxf(gb.y, pp.y);
                    float inter = fmaxf(iwd, 0.f) * fmaxf(ihd, 0.f);
                    float uni = sGA[g] + ab - inter;
                    float iou = inter / uni;
                    float cwd = fmaxf(gb.z, pp.z) - fminf(gb.x, pp.x);
                    float chd = fmaxf(gb.w, pp.w) - fminf(gb.y, pp.y);
                    float ac = fmaxf(cwd, 0.f) * fmaxf(chd, 0.f);
                    float giou = iou - (ac - uni) / ac;
                    float loss = 2.f * lcls + 5.f * cb - 2.f * giou;
                    val = -loss * SC;
                } else if (g == NGG) {
                    val = -ns * SC;   // background row
                }
            }
            e[i] = val;
        }
    }
    __syncthreads();   // geometry (in sA) fully read before first dump overwrites it

    const int r2 = tid >> 2, h = tid & 3;   // combine decomposition: 4 threads/row
    float vv = NEG;

    // ---- 100 Sinkhorn iterations ----
    for (int it = 0; it < NITER; ++it) {
        // Phase A: column LSE over this thread's 13 rows + 16-lane butterfly
        {
            float M = NEG;
            float xr[RPT];
            #pragma unroll
            for (int i = 0; i < RPT; ++i) {
                float x = e[i] + sU[r0 + i];
                xr[i] = x; M = fmaxf(M, x);
            }
            #pragma unroll
            for (int k = 1; k < 16; k <<= 1) M = fmaxf(M, __shfl_xor(M, k));
            float S = 0.f;
            #pragma unroll
            for (int i = 0; i < RPT; ++i) S += exp2f(xr[i] - M);
            #pragma unroll
            for (int k = 1; k < 16; k <<= 1) S += __shfl_xor(S, k);
            vv = -(M + log2f(S));
            if (col >= ncols) vv = NEG;   // pad col must not pollute row sums
        }
        // Phase B dump: raw a = e + v into sA[row][col]
        #pragma unroll
        for (int i = 0; i < RPT; ++i) sA[(r0 + i) * LDW + col] = e[i] + vv;
        __syncthreads();
        // Phase B combine: 4 threads/row, float4 LDS reads, per-WG (m,s) -> L3
        unsigned long long* pb = pms + ((size_t)(it & 1) * NIMG + img) * (RR * NWG);
        if (r2 < RR) {
            const float4* base = (const float4*)(sA + r2 * LDW + h * 16);
            float4 t0 = base[0], t1 = base[1], t2 = base[2], t3 = base[3];
            float M2 = fmaxf(
                fmaxf(fmaxf(fmaxf(t0.x, t0.y), fmaxf(t0.z, t0.w)),
                      fmaxf(fmaxf(t1.x, t1.y), fmaxf(t1.z, t1.w))),
                fmaxf(fmaxf(fmaxf(t2.x, t2.y), fmaxf(t2.z, t2.w)),
                      fmaxf(fmaxf(t3.x, t3.y), fmaxf(t3.z, t3.w))));
            #pragma unroll
            for (int k = 1; k < 4; k <<= 1) M2 = fmaxf(M2, __shfl_xor(M2, k));
            float S2 = exp2f(t0.x - M2) + exp2f(t0.y - M2) + exp2f(t0.z - M2) + exp2f(t0.w - M2)
                     + exp2f(t1.x - M2) + exp2f(t1.y - M2) + exp2f(t1.z - M2) + exp2f(t1.w - M2)
                     + exp2f(t2.x - M2) + exp2f(t2.y - M2) + exp2f(t2.z - M2) + exp2f(t2.w - M2)
                     + exp2f(t3.x - M2) + exp2f(t3.y - M2) + exp2f(t3.z - M2) + exp2f(t3.w - M2);
            #pragma unroll
            for (int k = 1; k < 4; k <<= 1) S2 += __shfl_xor(S2, k);
            if (h == 0) {
                MS ms; ms.f.x = M2; ms.f.y = S2;
                __hip_atomic_store(&pb[r2 * NWG + wg], ms.u,
                                   __ATOMIC_RELAXED, __HIP_MEMORY_SCOPE_AGENT);
            }
        }
        img_barrier(myc, (unsigned)NWG * (it + 1));
        // Phase C: 4 threads/row merge 16 WG partials -> U
        if (r2 < NR) {
            if (r2 < RR) {
                unsigned long long* pr = pb + r2 * NWG + h * 4;
                MS a0, a1, a2, a3;
                a0.u = __hip_atomic_load(&pr[0], __ATOMIC_RELAXED, __HIP_MEMORY_SCOPE_AGENT);
                a1.u = __hip_atomic_load(&pr[1], __ATOMIC_RELAXED, __HIP_MEMORY_SCOPE_AGENT);
                a2.u = __hip_atomic_load(&pr[2], __ATOMIC_RELAXED, __HIP_MEMORY_SCOPE_AGENT);
                a3.u = __hip_atomic_load(&pr[3], __ATOMIC_RELAXED, __HIP_MEMORY_SCOPE_AGENT);
                float gm = fmaxf(fmaxf(a0.f.x, a1.f.x), fmaxf(a2.f.x, a3.f.x));
                #pragma unroll
                for (int k = 1; k < 4; k <<= 1) gm = fmaxf(gm, __shfl_xor(gm, k));
                float S = a0.f.y * exp2f(a0.f.x - gm) + a1.f.y * exp2f(a1.f.x - gm)
                        + a2.f.y * exp2f(a2.f.x - gm) + a3.f.y * exp2f(a3.f.x - gm);
                #pragma unroll
                for (int k = 1; k < 4; k <<= 1) S += __shfl_xor(S, k);
                if (h == 0) sU[r2] = (r2 < NGG ? LMU2 : 0.f) - (gm + log2f(S));
            } else if (h == 0) {
                sU[r2] = NEG;   // pad rows must stay -inf (else Phase A corrupts)
            }
        }
        __syncthreads();
    }

    // ---- row max of X = E+U+V for pi normalization ----
    float u2[RPT];
    #pragma unroll
    for (int i = 0; i < RPT; ++i) u2[i] = sU[r0 + i];
    #pragma unroll
    for (int i = 0; i < RPT; ++i) sA[(r0 + i) * LDW + col] = e[i] + u2[i] + vv;
    __syncthreads();
    if (r2 < RR) {
        const float4* base = (const float4*)(sA + r2 * LDW + h * 16);
        float4 t0 = base[0], t1 = base[1], t2 = base[2], t3 = base[3];
        float M2 = fmaxf(
            fmaxf(fmaxf(fmaxf(t0.x, t0.y), fmaxf(t0.z, t0.w)),
                  fmaxf(fmaxf(t1.x, t1.y), fmaxf(t1.z, t1.w))),
            fmaxf(fmaxf(fmaxf(t2.x, t2.y), fmaxf(t2.z, t2.w)),
                  fmaxf(fmaxf(t3.x, t3.y), fmaxf(t3.z, t3.w))));
        #pragma unroll
        for (int k = 1; k < 4; k <<= 1) M2 = fmaxf(M2, __shfl_xor(M2, k));
        if (h == 0)
            __hip_atomic_store(&pmx[((size_t)img * RR + r2) * NWG + wg], M2,
                               __ATOMIC_RELAXED, __HIP_MEMORY_SCOPE_AGENT);
    }
    img_barrier(myc, (unsigned)NWG * (NITER + 1));
    if (r2 < NR) {
        if (r2 < RR) {
            float* px = pmx + ((size_t)img * RR + r2) * NWG + h * 4;
            float M = fmaxf(
                fmaxf(__hip_atomic_load(&px[0], __ATOMIC_RELAXED, __HIP_MEMORY_SCOPE_AGENT),
                      __hip_atomic_load(&px[1], __ATOMIC_RELAXED, __HIP_MEMORY_SCOPE_AGENT)),
                fmaxf(__hip_atomic_load(&px[2], __ATOMIC_RELAXED, __HIP_MEMORY_SCOPE_AGENT),
                      __hip_atomic_load(&px[3], __ATOMIC_RELAXED, __HIP_MEMORY_SCOPE_AGENT)));
            #pragma unroll
            for (int k = 1; k < 4; k <<= 1) M = fmaxf(M, __shfl_xor(M, k));
            if (h == 0) sRM[r2] = M;
        } else if (h == 0) sRM[r2] = 0.f;
    }
    __syncthreads();

    // ---- argmax (log-domain key; strict > ascending + min-index tie-break
    //      == numpy first-index argmax; vv is col-constant, argmax-invariant) ----
    {
        float bv = -3.0e38f; int bi = 0;
        #pragma unroll
        for (int i = 0; i < RPT; ++i) {
            int r = r0 + i;
            float key = e[i] + u2[i] - sRM[r];
            if (r < RR && key > bv) { bv = key; bi = r; }
        }
        #pragma unroll
        for (int k = 1; k < 16; k <<= 1) {
            float ov = __shfl_xor(bv, k); int oi = __shfl_xor(bi, k);
            if (ov > bv || (ov == bv && oi < bi)) { bv = ov; bi = oi; }
        }
        if (part == 0 && col < ncols)
            out[(size_t)NIMG * RR * NQI + (size_t)img * NQI + q] = (float)bi;
    }

    // ---- pi output via chunked LDS transpose (coalesced 256B row stores) ----
    for (int c = 0; c < 4; ++c) {
        __syncthreads();
        if ((part >> 2) == c && col < ncols) {
            #pragma unroll
            for (int i = 0; i < RPT; ++i) {
                int r = r0 + i;               // in [52c, 52c+51]
                if (r < RR)
                    sA[(r - 52 * c) * LDW + col] = exp2f(e[i] + u2[i] + vv - sRM[r]);
            }
        }
        __syncthreads();
        int rl = tid >> 6, colj = tid & 63;
        #pragma unroll
        for (int t = 0; t < 4; ++t) {
            int rr = rl + 16 * t, rg = 52 * c + rr;
            if (rr < 52 && rg < RR && colj < ncols)
                out[((size_t)img * RR + rg) * NQI + (q0 + colj)] = sA[rr * LDW + colj];
        }
    }
}

extern "C" void kernel_launch(void* const* d_in, const int* in_sizes, int n_in,
                              void* d_out, int out_size, void* d_ws, size_t ws_size,
                              hipStream_t stream) {
    const float* logits = (const float*)d_in[0];
    const float* pboxes = (const float*)d_in[1];
    const int*   gcls   = (const int*)  d_in[2];
    const float* gboxes = (const float*)d_in[3];
    const float* imsz   = (const float*)d_in[4];
    const float* imszt  = (const float*)d_in[5];
    float* out = (float*)d_out;

    unsigned* cnt = (unsigned*)d_ws;                                     // 16 ctrs, 64B apart
    unsigned long long* pms = (unsigned long long*)((char*)d_ws + 1024); // 823,296 B
    float* pmx = (float*)((char*)d_ws + 1024 + 2ull * NIMG * RR * NWG * 8); // 205,824 B

    // barrier counters must start at 0 every call (graph replays don't re-poison)
    hipMemsetAsync(d_ws, 0, 1024, stream);

    ota_kernel<<<dim3(256), dim3(NTHR), 0, stream>>>(
        logits, pboxes, gcls, gboxes, imsz, imszt, out, cnt, pms, pmx);
}